// Round 1
// baseline (377.093 us; speedup 1.0000x reference)
//
#include <hip/hip_runtime.h>
#include <math.h>

// MLA decode attention (fp32), flash-decoding split over sequence chunks.
// B=64, H=16, latent D=576, V=512, MAX_LEN=4096.
//
// Kernel A (mla_chunk): grid (nchunk, B), 256 threads (4 waves).
//   Block processes rows [c*chunk, min((c+1)*chunk,total)) for all 16 heads,
//   online softmax over 32-row tiles:
//     phase 1: 4 waves x 4 rows, 16 d-lanes per row; coalesced float4 loads
//              (row == newpos substitutes key_value_states — cache is never
//              mutated); V-part staged to LDS; 16 head-dots per lane;
//              reduce-scatter butterfly leaves head dd's score in lane dd.
//     phase 2: per-head tile max / exp / l update (16 threads per head).
//     phase 3: PV: thread owns v=2t,2t+1 for all heads; V from LDS (no HBM
//              re-read), p broadcast from LDS.
//   Writes per-(b,c,h) partial out[512] + (m,l) to workspace.
// Kernel B (mla_reduce): standard flash-decoding chunk merge.

namespace {
constexpr int NB = 64;
constexpr int NH = 16;
constexpr int MAXLEN = 4096;
constexpr int D = 576;
constexpr int DV = 512;
constexpr int NF4 = D / 64;   // 9 float4 per lane-slice
constexpr int TR = 32;        // tile rows
constexpr float SCALE = 0.041666666666666664f;
constexpr float NEGINF = -1e30f;
}

__global__ __launch_bounds__(256)
void mla_chunk(const float* __restrict__ qg,
               const float* __restrict__ kvnew,
               const float* __restrict__ cache,
               const int* __restrict__ lens,
               float* __restrict__ ws_o,
               float* __restrict__ ws_ml,
               int nchunk, int chunk)
{
    const int c = blockIdx.x;
    const int b = blockIdx.y;
    const int tid = (int)threadIdx.x;

    const int total = lens[b] + 1;
    const int start = c * chunk;
    if (start >= total) return;           // uniform early-exit, no barriers yet
    const int end = min(start + chunk, total);
    const int newpos = total - 1;

    __shared__ float q_s[NH][D];        // 36864 B
    __shared__ float row_s[TR][DV];     // 65536 B  (V-part staging)
    __shared__ float p_s[TR][NH];       // 2048 B
    __shared__ float scl_s[NH];

    {   // load Q for this batch: 2304 float4, coalesced
        const float4* qsrc = (const float4*)(qg + (size_t)b * NH * D);
        float4* qdst = (float4*)&q_s[0][0];
        #pragma unroll
        for (int i = 0; i < (NH * D / 4) / 256; ++i)
            qdst[tid + 256 * i] = qsrc[tid + 256 * i];
    }
    __syncthreads();

    const int wave = tid >> 6;
    const int lane = tid & 63;
    const int rr = lane >> 4;     // row within 4-row quad
    const int dd = lane & 15;     // d-slice index
    const int h_my = tid >> 4;    // phase-2 role: head
    const int rs = tid & 15;      // phase-2 role: row-slice

    float acc0[NH], acc1[NH];     // PV accumulators: v = 2*tid, 2*tid+1
    #pragma unroll
    for (int h = 0; h < NH; ++h) { acc0[h] = 0.f; acc1[h] = 0.f; }
    float m_run = NEGINF, l_run = 0.f;

    for (int r0 = start; r0 < end; r0 += TR) {
        // ---- phase 1: scores + stage V ----
        #pragma unroll
        for (int pass = 0; pass < 2; ++pass) {
            const int rl = (wave + 4 * pass) * 4 + rr;   // local row 0..31
            const int row = r0 + rl;
            const bool valid = row < end;
            const float* src = (row == newpos)
                ? (kvnew + (size_t)b * D)
                : (cache + ((size_t)b * MAXLEN + row) * D);
            float4 x[NF4];
            #pragma unroll
            for (int j = 0; j < NF4; ++j) {
                if (valid) x[j] = *(const float4*)(src + j * 64 + dd * 4);
                else       x[j] = make_float4(0.f, 0.f, 0.f, 0.f);
            }
            // stage V-part (d < 512) for the PV phase
            #pragma unroll
            for (int j = 0; j < 8; ++j)
                *(float4*)&row_s[rl][j * 64 + dd * 4] = x[j];

            float sa[NH];
            #pragma unroll
            for (int h = 0; h < NH; ++h) {
                const float4* qp = (const float4*)&q_s[h][0];
                float s = 0.f;
                #pragma unroll
                for (int j = 0; j < NF4; ++j) {
                    float4 qv = qp[j * 16 + dd];
                    s = fmaf(x[j].x, qv.x, s);
                    s = fmaf(x[j].y, qv.y, s);
                    s = fmaf(x[j].z, qv.z, s);
                    s = fmaf(x[j].w, qv.w, s);
                }
                sa[h] = s;
            }
            // reduce-scatter butterfly across the 16 d-lanes: after 4 steps
            // lane dd holds the complete dot for head dd. All register
            // indices static (runtime-indexed arrays would spill).
            #pragma unroll
            for (int s = 0; s < 4; ++s) {
                const int m = 1 << s;
                const int bit = (dd >> s) & 1;
                #pragma unroll
                for (int j = 0; j < (NH >> (s + 1)); ++j) {
                    float keep = bit ? sa[2 * j + 1] : sa[2 * j];
                    float send = bit ? sa[2 * j]     : sa[2 * j + 1];
                    sa[j] = keep + __shfl_xor(send, m);
                }
            }
            p_s[rl][dd] = valid ? sa[0] * SCALE : NEGINF;
        }
        __syncthreads();

        // ---- phase 2: per-head online-softmax update ----
        {
            float s0 = p_s[rs][h_my];
            float s1 = p_s[rs + 16][h_my];
            float tm = fmaxf(s0, s1);
            #pragma unroll
            for (int m = 1; m < 16; m <<= 1)
                tm = fmaxf(tm, __shfl_xor(tm, m));
            const float m_new = fmaxf(m_run, tm);
            const float scl = expf(m_run - m_new);
            const float p0 = expf(s0 - m_new);
            const float p1 = expf(s1 - m_new);
            p_s[rs][h_my] = p0;
            p_s[rs + 16][h_my] = p1;
            float ls = p0 + p1;
            #pragma unroll
            for (int m = 1; m < 16; m <<= 1)
                ls += __shfl_xor(ls, m);
            l_run = l_run * scl + ls;
            m_run = m_new;
            if (rs == 0) scl_s[h_my] = scl;
        }
        __syncthreads();

        // ---- phase 2b: rescale accumulators ----
        {
            const float4* sc4 = (const float4*)&scl_s[0];
            float scl[NH];
            #pragma unroll
            for (int g = 0; g < 4; ++g) {
                float4 v = sc4[g];
                scl[4*g+0] = v.x; scl[4*g+1] = v.y;
                scl[4*g+2] = v.z; scl[4*g+3] = v.w;
            }
            #pragma unroll
            for (int h = 0; h < NH; ++h) { acc0[h] *= scl[h]; acc1[h] *= scl[h]; }
        }
        // ---- phase 3: PV from LDS ----
        const int nrl = min(TR, end - r0);
        for (int rl = 0; rl < nrl; ++rl) {
            const float2 x = *(const float2*)&row_s[rl][2 * tid];
            const float4* pp = (const float4*)&p_s[rl][0];
            float p[NH];
            #pragma unroll
            for (int g = 0; g < 4; ++g) {
                float4 v = pp[g];
                p[4*g+0] = v.x; p[4*g+1] = v.y;
                p[4*g+2] = v.z; p[4*g+3] = v.w;
            }
            #pragma unroll
            for (int h = 0; h < NH; ++h) {
                acc0[h] = fmaf(p[h], x.x, acc0[h]);
                acc1[h] = fmaf(p[h], x.y, acc1[h]);
            }
        }
        __syncthreads();
    }

    // ---- write partial results ----
    const size_t obase = (((size_t)b * nchunk + c) * NH) * (size_t)DV;
    #pragma unroll
    for (int h = 0; h < NH; ++h) {
        *(float2*)&ws_o[obase + (size_t)h * DV + 2 * tid] =
            make_float2(acc0[h], acc1[h]);
    }
    if (rs == 0) {
        const size_t mlb = (((size_t)b * nchunk + c) * NH + h_my) * 2;
        ws_ml[mlb + 0] = m_run;
        ws_ml[mlb + 1] = l_run;
    }
}

__global__ __launch_bounds__(256)
void mla_reduce(const int* __restrict__ lens,
                const float* __restrict__ ws_o,
                const float* __restrict__ ws_ml,
                float* __restrict__ out,
                int nchunk, int chunk)
{
    const int h = blockIdx.x;
    const int b = blockIdx.y;
    const int tid = (int)threadIdx.x;
    const int total = lens[b] + 1;
    const int nact = min(nchunk, (total + chunk - 1) / chunk);

    float M = NEGINF;
    for (int c = 0; c < nact; ++c)
        M = fmaxf(M, ws_ml[(((size_t)b * nchunk + c) * NH + h) * 2]);

    float a0 = 0.f, a1 = 0.f, L = 0.f;
    for (int c = 0; c < nact; ++c) {
        const size_t mlb = (((size_t)b * nchunk + c) * NH + h) * 2;
        const float w = expf(ws_ml[mlb] - M);
        L += w * ws_ml[mlb + 1];
        const float2 o = *(const float2*)&ws_o[
            (((size_t)b * nchunk + c) * NH + h) * (size_t)DV + 2 * tid];
        a0 = fmaf(w, o.x, a0);
        a1 = fmaf(w, o.y, a1);
    }
    const float inv = 1.f / L;
    *(float2*)&out[((size_t)b * NH + h) * (size_t)DV + 2 * tid] =
        make_float2(a0 * inv, a1 * inv);
}

extern "C" void kernel_launch(void* const* d_in, const int* in_sizes, int n_in,
                              void* d_out, int out_size, void* d_ws, size_t ws_size,
                              hipStream_t stream)
{
    (void)in_sizes; (void)n_in; (void)out_size;
    const float* qg    = (const float*)d_in[0];   // [B,H,576]
    const float* kvnew = (const float*)d_in[1];   // [B,1,576]
    const float* cache = (const float*)d_in[2];   // [B,4096,576]
    const int*   lens  = (const int*)d_in[3];     // [B]
    float* out = (float*)d_out;                   // [B,H,512] fp32

    // pick largest chunk split that fits the workspace (32 MB at nchunk=16)
    int nchunk = 16;
    while (nchunk > 1 &&
           (size_t)NB * nchunk * NH * (DV + 2) * sizeof(float) > ws_size)
        nchunk >>= 1;
    const int chunk = MAXLEN / nchunk;

    float* ws_o  = (float*)d_ws;
    float* ws_ml = ws_o + (size_t)NB * nchunk * NH * DV;

    dim3 gA(nchunk, NB);
    mla_chunk<<<gA, 256, 0, stream>>>(qg, kvnew, cache, lens, ws_o, ws_ml,
                                      nchunk, chunk);
    dim3 gB(NH, NB);
    mla_reduce<<<gB, 256, 0, stream>>>(lens, ws_o, ws_ml, out, nchunk, chunk);
}